// Round 7
// baseline (327.955 us; speedup 1.0000x reference)
//
#include <hip/hip_runtime.h>
#include <stdint.h>

typedef unsigned int u32;
typedef unsigned long long u64;
typedef unsigned short u16;
typedef __attribute__((ext_vector_type(8))) short bf16x8;
typedef __attribute__((ext_vector_type(4))) float f32x4;

#define S_ 1024
#define D_ 64
#define NH_ 64
#define BINS_ 16384
#define BSHIFT_ 18
#define TOPK_ 4096u
#define SAMP_ 4u
#define LCAP_ 16384
#define BCAP_ 1280
#define RCAP_ 48
#define TCAP_ 512
#define CNTSTRIDE_ 32          // pad per-head counters to 128B (XCD false-sharing fix)
#define EPS_ 1e-5f
#define LOGN_ 13.862943611198906f   // log(1024*1024)

__device__ __forceinline__ u32 mono_key(float s){
  u32 u = __float_as_uint(s);
  return (u >> 31) ? ~u : (u | 0x80000000u);   // ascending monotone map
}
__device__ __forceinline__ u16 f2b(float f){
  u32 u = __float_as_uint(f);
  return (u16)((u + 0x7FFFu + ((u >> 16) & 1u)) >> 16);   // f32 -> bf16 RNE
}
__device__ __forceinline__ float b2f(u16 b){
  return __uint_as_float(((u32)b) << 16);
}

// ---------------- K1: inverse norms + normalized bf16 Q,K ----------------
__global__ __launch_bounds__(256) void k1_norm(const float* __restrict__ Q,
    const float* __restrict__ K, float* __restrict__ qinv, float* __restrict__ kinv,
    u16* __restrict__ Qn, u16* __restrict__ Kn){
  int gw = (int)((blockIdx.x * blockDim.x + threadIdx.x) >> 6);
  int d = threadIdx.x & 63;
  if (gw >= 2 * NH_ * S_) return;
  const float* src; float* dst; u16* bdst; int row;
  if (gw < NH_ * S_){ src = Q; dst = qinv; bdst = Qn; row = gw; }
  else               { src = K; dst = kinv; bdst = Kn; row = gw - NH_ * S_; }
  float x = src[(u64)row * D_ + d];
  float ss = x * x;
  #pragma unroll
  for (int m = 32; m; m >>= 1) ss += __shfl_xor(ss, m, 64);
  float inv = 1.0f / (sqrtf(ss) + EPS_);
  if (d == 0) dst[row] = inv;
  bdst[(u64)row * D_ + d] = f2b(x * inv);
}

// ---------------- K1b: V -> VT (bf16, [h][d][k]) via LDS transpose ----------------
__global__ __launch_bounds__(256) void k1b_vt(const float* __restrict__ V,
                                             u16* __restrict__ VT){
  __shared__ u16 tr[64 * 65];
  const int t = threadIdx.x;
  const int h = blockIdx.x >> 4, k0 = (blockIdx.x & 15) * 64;
  for (int idx = t; idx < 4096; idx += 256){
    int r = idx >> 6, d = idx & 63;
    tr[d * 65 + r] = f2b(V[((u64)(h * S_ + k0 + r)) * D_ + d]);
  }
  __syncthreads();
  for (int idx = t; idx < 4096; idx += 256){
    int dr = idx >> 6, c = idx & 63;
    VT[((u64)(h * D_ + dr)) * S_ + k0 + c] = tr[dr * 65 + c];
  }
}

// ---------------- K2: sampled histogram via MFMA (4 blocks per head, XCD-local) ----------------
__global__ __launch_bounds__(512) void k2_hist(const u16* __restrict__ Qn,
    const u16* __restrict__ Kn, u32* __restrict__ Hist){
  __shared__ u32 hist[BINS_];                               // 64KB
  __shared__ __attribute__((aligned(16))) u16 kt2[64 * 64]; // 8KB
  const int t = threadIdx.x, h = blockIdx.x & 63, st = blockIdx.x >> 6;
  const int w = t >> 6, l = t & 63, lr = l & 15, lg = l >> 4;
  for (int i = t; i < BINS_; i += 512) hist[i] = 0u;
  const int k0 = (st * 4 + 1) * 64;   // sampled k-tiles {1,5,9,13}
  __syncthreads();
  { int srow = t >> 3, sslot = t & 7;
    *(uint4*)(kt2 + srow * 64 + ((sslot ^ (srow & 7)) * 8)) =
      *(const uint4*)(Kn + ((u64)(h * S_ + k0 + srow)) * D_ + sslot * 8);
  }
  __syncthreads();
  for (int qc = 0; qc < 8; ++qc){
    const u16* qrow = Qn + ((u64)(h * S_ + qc * 128 + w * 16 + lr)) * D_;
    bf16x8 qa0 = *(const bf16x8*)(qrow + lg * 8);
    bf16x8 qa1 = *(const bf16x8*)(qrow + lg * 8 + 32);
    #pragma unroll
    for (int j = 0; j < 4; ++j){
      int krow = j * 16 + lr, sw = krow & 7;
      bf16x8 kb0 = *(const bf16x8*)(kt2 + krow * 64 + ((lg ^ sw) * 8));
      bf16x8 kb1 = *(const bf16x8*)(kt2 + krow * 64 + (((lg + 4) ^ sw) * 8));
      f32x4 sa = {0.f, 0.f, 0.f, 0.f};
      sa = __builtin_amdgcn_mfma_f32_16x16x32_bf16(qa0, kb0, sa, 0, 0, 0);
      sa = __builtin_amdgcn_mfma_f32_16x16x32_bf16(qa1, kb1, sa, 0, 0, 0);
      #pragma unroll
      for (int r = 0; r < 4; ++r)
        atomicAdd(&hist[mono_key(sa[r]) >> BSHIFT_], 1u);
    }
  }
  __syncthreads();
  for (int i = t; i < BINS_; i += 512){
    u32 c = hist[i];
    if (c) atomicAdd(&Hist[(u64)h * BINS_ + i], c);
  }
}

// ---------------- K3: suffix scan (sampled counts x SAMP) -> weight table + bstar ----------------
__global__ __launch_bounds__(256) void k3_scan(
    const u32* __restrict__ Hist, u16* __restrict__ Wb, u32* __restrict__ bstar)
{
  __shared__ u32 csum[256];
  const int h = blockIdx.x, t = threadIdx.x;
  const u32* Hh = Hist + (u64)h * BINS_;
  u32 local = 0;
  for (int i = 0; i < 64; ++i) local += Hh[t * 64 + i];
  csum[t] = local;
  __syncthreads();
  for (int off = 1; off < 256; off <<= 1){
    u32 v = (t + off < 256) ? csum[t + off] : 0u;
    __syncthreads();
    csum[t] += v;
    __syncthreads();
  }
  u32 g = csum[t] - local;     // sampled count strictly above this thread's bins
  u32 bmin = 0xFFFFFFFFu;
  for (int i = 63; i >= 0; --i){
    int bin = t * 64 + i;
    u32 c = Hh[bin];
    float wmid = LOGN_ - logf((float)(SAMP_ * g) + 0.5f * ((float)(SAMP_ * c) + 1.0f));
    Wb[(u64)h * BINS_ + bin] = f2b(wmid);
    if (SAMP_ * g < TOPK_) bmin = (u32)bin;
    g += c;
  }
  if (bmin != 0xFFFFFFFFu) atomicMin(&bstar[h], bmin);
}

// ---------------- K4: swapped MFMA QK^T -> bin/gather -> shfl-exchange -> MFMA W@V ----------------
// grid: 512 blocks, h = blk&63 (XCD-local), q0 = (blk>>6)*128; block 512 (8 waves)
__global__ __launch_bounds__(512, 4) void k4_main(
    const u16* __restrict__ Qn, const u16* __restrict__ Kn, const u16* __restrict__ VT,
    const u16* __restrict__ Wb, const u32* __restrict__ bstar,
    u32* __restrict__ listCount, u64* __restrict__ list,
    float* __restrict__ Zrow, float* __restrict__ out)
{
  __shared__ u16 wbl[BINS_];                                 // 32KB
  __shared__ __attribute__((aligned(16))) u16 kt2[64 * 64];  // 8KB
  __shared__ __attribute__((aligned(16))) u16 vt2[64 * 64];  // 8KB
  __shared__ u64 blist[BCAP_];                               // 10KB
  __shared__ u32 bcnt, gbase;
  const int t = threadIdx.x;
  const int h = blockIdx.x & 63;
  const int q0 = (blockIdx.x >> 6) * 128;
  const int w = t >> 6, l = t & 63, lr = l & 15, lg = l >> 4;

  for (int i = t; i < BINS_; i += 512) wbl[i] = Wb[(u64)h * BINS_ + i];
  if (t == 0) bcnt = 0;
  const u32 bst = bstar[h];
  const int qrow_g = q0 + w * 16 + lr;     // this lane's q row (owns it for QK^T output)

  const u16* qrow = Qn + ((u64)(h * S_ + qrow_g)) * D_;
  bf16x8 qa0 = *(const bf16x8*)(qrow + lg * 8);
  bf16x8 qa1 = *(const bf16x8*)(qrow + lg * 8 + 32);

  f32x4 acc[4] = {{0,0,0,0},{0,0,0,0},{0,0,0,0},{0,0,0,0}};
  float zacc = 0.f;
  const int srow = t >> 3, sslot = t & 7;
  const int srcA = lr + ((lg & 1) << 5);   // exchange partners for W A-frag assembly
  const int srcB = srcA + 16;
  const bool jhi = (lg >> 1) != 0;

  // prefetch tile 0 into registers
  uint4 kreg = *(const uint4*)(Kn + ((u64)(h * S_ + srow)) * D_ + sslot * 8);
  uint4 vreg = *(const uint4*)(VT + ((u64)(h * D_ + srow)) * S_ + sslot * 8);

  for (int kt0 = 0; kt0 < 16; ++kt0){
    const int k0 = kt0 * 64;
    __syncthreads();   // prev tile's readers of kt2/vt2 done (covers wbl/bcnt init, 1st iter)
    *(uint4*)(kt2 + srow * 64 + ((sslot ^ (srow & 7)) * 8)) = kreg;
    *(uint4*)(vt2 + srow * 64 + ((sslot ^ (srow & 7)) * 8)) = vreg;
    __syncthreads();   // staged
    if (kt0 < 15){     // issue next tile's loads early; they complete under compute
      const int kn0 = k0 + 64;
      kreg = *(const uint4*)(Kn + ((u64)(h * S_ + kn0 + srow)) * D_ + sslot * 8);
      vreg = *(const uint4*)(VT + ((u64)(h * D_ + srow)) * S_ + kn0 + sslot * 8);
    }

    // QK^T swapped: sa = K_tile16 x Q_16 -> lane (lr,lg) reg r = S[q=qrow_g][k0+j*16+lg*4+r]
    u32 Plo[4], Phi[4];
    #pragma unroll
    for (int j = 0; j < 4; ++j){
      int krow = j * 16 + lr, sw = krow & 7;
      bf16x8 kb0 = *(const bf16x8*)(kt2 + krow * 64 + ((lg ^ sw) * 8));
      bf16x8 kb1 = *(const bf16x8*)(kt2 + krow * 64 + (((lg + 4) ^ sw) * 8));
      f32x4 sa = {0.f, 0.f, 0.f, 0.f};
      sa = __builtin_amdgcn_mfma_f32_16x16x32_bf16(kb0, qa0, sa, 0, 0, 0);
      sa = __builtin_amdgcn_mfma_f32_16x16x32_bf16(kb1, qa1, sa, 0, 0, 0);
      u32 wb4[4];
      #pragma unroll
      for (int r = 0; r < 4; ++r){
        u32 key = mono_key(sa[r]);
        u32 bin = key >> BSHIFT_;
        u32 wbits = (u32)wbl[bin];
        wb4[r] = wbits;
        zacc += b2f((u16)wbits);
        if (bin >= bst){
          u32 pos = ((u32)qrow_g << 10) | (u32)(k0 + j * 16 + lg * 4 + r);
          u64 ent = ((u64)wbits << 32) | (u64)pos;
          u32 li = atomicAdd(&bcnt, 1u);         // LDS atomic: block-local
          if (li < BCAP_) blist[li] = ent;
          else {                                  // rare overflow: direct reserve
            u32 gi = atomicAdd(&listCount[h * CNTSTRIDE_], 1u);
            if (gi < LCAP_) list[(u64)h * LCAP_ + gi] = ent;
          }
        }
      }
      Plo[j] = wb4[0] | (wb4[1] << 16);
      Phi[j] = wb4[2] | (wb4[3] << 16);
    }

    // in-register exchange: build A-frag W[q=lr][k = lg*8..] from partner lanes
    u32 s0 = (u32)__shfl((int)Plo[0], srcA, 64), s1 = (u32)__shfl((int)Phi[0], srcA, 64);
    u32 s2 = (u32)__shfl((int)Plo[1], srcA, 64), s3 = (u32)__shfl((int)Phi[1], srcA, 64);
    u32 s4 = (u32)__shfl((int)Plo[2], srcA, 64), s5 = (u32)__shfl((int)Phi[2], srcA, 64);
    u32 s6 = (u32)__shfl((int)Plo[3], srcA, 64), s7 = (u32)__shfl((int)Phi[3], srcA, 64);
    u32 r0 = (u32)__shfl((int)Plo[0], srcB, 64), r1 = (u32)__shfl((int)Phi[0], srcB, 64);
    u32 r2 = (u32)__shfl((int)Plo[1], srcB, 64), r3 = (u32)__shfl((int)Phi[1], srcB, 64);
    u32 r4 = (u32)__shfl((int)Plo[2], srcB, 64), r5 = (u32)__shfl((int)Phi[2], srcB, 64);
    u32 r6 = (u32)__shfl((int)Plo[3], srcB, 64), r7 = (u32)__shfl((int)Phi[3], srcB, 64);
    union { u32 u[4]; bf16x8 v; } W0, W1;
    W0.u[0] = jhi ? s2 : s0;  W0.u[1] = jhi ? s3 : s1;
    W0.u[2] = jhi ? r2 : r0;  W0.u[3] = jhi ? r3 : r1;
    W1.u[0] = jhi ? s6 : s4;  W1.u[1] = jhi ? s7 : s5;
    W1.u[2] = jhi ? r6 : r4;  W1.u[3] = jhi ? r7 : r5;

    // W @ V-tile
    #pragma unroll
    for (int dt = 0; dt < 4; ++dt){
      int rv = dt * 16 + lr, swv = rv & 7;
      bf16x8 vb0 = *(const bf16x8*)(vt2 + rv * 64 + ((lg ^ swv) * 8));
      bf16x8 vb1 = *(const bf16x8*)(vt2 + rv * 64 + (((lg + 4) ^ swv) * 8));
      acc[dt] = __builtin_amdgcn_mfma_f32_16x16x32_bf16(W0.v, vb0, acc[dt], 0, 0, 0);
      acc[dt] = __builtin_amdgcn_mfma_f32_16x16x32_bf16(W1.v, vb1, acc[dt], 0, 0, 0);
    }
  }

  // flush the block-local candidate list with ONE global atomic
  __syncthreads();
  u32 cnt = bcnt; if (cnt > BCAP_) cnt = BCAP_;
  if (t == 0) gbase = atomicAdd(&listCount[h * CNTSTRIDE_], cnt);
  __syncthreads();
  for (u32 i = t; i < cnt; i += 512){
    u32 gi = gbase + i;
    if (gi < LCAP_) list[(u64)h * LCAP_ + gi] = blist[i];
  }

  // write out (pre-normalization): lane (lr,lg) reg r -> out[q0+16w+lg*4+r][dt*16+lr]
  #pragma unroll
  for (int r = 0; r < 4; ++r){
    int q = q0 + 16 * w + lg * 4 + r;
    #pragma unroll
    for (int dt = 0; dt < 4; ++dt)
      out[((u64)(h * S_ + q)) * D_ + dt * 16 + lr] = acc[dt][r];
  }
  // z: lane holds partial over its 16 k per tile; reduce across lg group
  zacc += __shfl_xor(zacc, 16, 64);
  zacc += __shfl_xor(zacc, 32, 64);
  if (lg == 0) Zrow[h * S_ + qrow_g] = zacc;
}

// ---------------- K5a: exact f32 rescoring (wave-parallel dot) + key min/max ----------------
// grid: 256 blocks (h = blk&63); block 256 = 4 waves; 16 lanes per entry
__global__ __launch_bounds__(256) void k5a_score(
    const float* __restrict__ Q, const float* __restrict__ K,
    const float* __restrict__ qinv, const float* __restrict__ kinv,
    const u64* __restrict__ list, const u32* __restrict__ listCount,
    u64* __restrict__ keyex, u16* __restrict__ wbx,
    u32* __restrict__ kminb, u32* __restrict__ kmaxb)
{
  const int h = blockIdx.x & 63, sub = blockIdx.x >> 6, t = threadIdx.x;
  const int wv = t >> 6, l = t & 63, seg = l & 15, sl = l >> 4;
  const int widx = sub * 4 + wv;   // 0..15 across the head
  u32 T = listCount[h * CNTSTRIDE_]; if (T > LCAP_) T = LCAP_;
  u32 kmn = 0xFFFFFFFFu, kmx = 0u;
  for (u32 eb = (u32)(widx * 4); eb < T; eb += 64u){
    u32 e = eb + (u32)sl;
    bool valid = (e < T);
    u64 ent = valid ? list[(u64)h * LCAP_ + e] : 0ull;
    u32 pos = (u32)ent;
    u32 q = pos >> 10, k = pos & 1023u;
    float s = 0.f;
    if (valid){
      float4 a = *(const float4*)(Q + ((u64)(h * S_ + q)) * D_ + seg * 4);
      float4 b = *(const float4*)(K + ((u64)(h * S_ + k)) * D_ + seg * 4);
      s = a.x * b.x + a.y * b.y + a.z * b.z + a.w * b.w;
    }
    s += __shfl_xor(s, 1, 64);
    s += __shfl_xor(s, 2, 64);
    s += __shfl_xor(s, 4, 64);
    s += __shfl_xor(s, 8, 64);
    if (valid && seg == 0){
      s *= qinv[h * S_ + q] * kinv[h * S_ + k];
      u32 key = mono_key(s);
      keyex[(u64)h * LCAP_ + e] = ((u64)key << 32) | (u64)(0xFFFFFFFFu - pos);
      wbx[(u64)h * LCAP_ + e] = (u16)(ent >> 32);
      kmn = key < kmn ? key : kmn;
      kmx = key > kmx ? key : kmx;
    }
  }
  #pragma unroll
  for (int m = 1; m < 64; m <<= 1){
    u32 a = __shfl_xor(kmn, m, 64); kmn = kmn < a ? kmn : a;
    u32 b = __shfl_xor(kmx, m, 64); kmx = kmx > b ? kmx : b;
  }
  if (l == 0){
    atomicMin(&kminb[h * CNTSTRIDE_], kmn);
    atomicMax(&kmaxb[h * CNTSTRIDE_], kmx);
  }
}

// ---------------- K5b: fine-histogram ranks; exact top via same-bin topset ----------------
// grid: 64 blocks (1 per head) x 1024
__global__ __launch_bounds__(1024) void k5b_rank(
    const u64* __restrict__ keyex, const u16* __restrict__ wbx,
    const u32* __restrict__ listCount,
    const u32* __restrict__ kminb, const u32* __restrict__ kmaxb,
    u32* __restrict__ rowcnt, u32* __restrict__ rowk, float* __restrict__ rowdw)
{
  __shared__ u32 fh[BINS_];      // 64KB fine histogram -> strict-above counts
  __shared__ u32 rcnt[S_];       // 4KB per-row emission counts
  __shared__ u32 psum[1024];     // 4KB
  __shared__ u64 tkey[TCAP_];    // 4KB topset entries
  __shared__ u32 tidx[TCAP_];    // 2KB topset list indices
  __shared__ u32 topcnt;
  const int h = blockIdx.x, t = threadIdx.x;
  u32 T = listCount[h * CNTSTRIDE_]; if (T > LCAP_) T = LCAP_;
  const u64* lh = keyex + (u64)h * LCAP_;
  const u32 base = kminb[h * CNTSTRIDE_];
  const u32 range = kmaxb[h * CNTSTRIDE_] - base;
  int sh = 0;
  while ((range >> sh) >= (u32)BINS_) ++sh;

  for (int i = t; i < BINS_; i += 1024) fh[i] = 0u;
  for (int i = t; i < S_; i += 1024) rcnt[i] = 0u;
  if (t == 0) topcnt = 0u;
  __syncthreads();

  // pass 1: fine histogram
  for (u32 e = (u32)t; e < T; e += 1024u){
    u32 k = (u32)(lh[e] >> 32);
    atomicAdd(&fh[(k - base) >> sh], 1u);
  }
  __syncthreads();

  // suffix scan: fh[b] := count of elements in bins strictly greater than b
  u32 local = 0;
  for (int i = 0; i < 16; ++i) local += fh[t * 16 + i];
  psum[t] = local;
  __syncthreads();
  for (int off = 1; off < 1024; off <<= 1){
    u32 v = (t + off < 1024) ? psum[t + off] : 0u;
    __syncthreads();
    psum[t] += v;
    __syncthreads();
  }
  u32 g = psum[t] - local;
  for (int i = 15; i >= 0; --i){
    int b = t * 16 + i;
    u32 c = fh[b];
    fh[b] = g;
    g += c;
  }
  __syncthreads();

  // pass 2: bulk midpoint ranks; collect topset (gs<64 => all same-bin peers collected)
  for (u32 e = (u32)t; e < T; e += 1024u){
    u64 ent = lh[e];
    u32 k = (u32)(ent >> 32);
    u32 fb = (k - base) >> sh;
    u32 gs = fh[fb];                       // strictly above by bin
    if (gs < 64u){
      u32 ti = atomicAdd(&topcnt, 1u);
      if (ti < TCAP_){ tkey[ti] = ent; tidx[ti] = e; continue; }
    }
    u32 ge = (fb == 0u) ? T : fh[fb - 1];  // above-or-equal bin total
    float c = (float)(ge - gs);
    float wex = LOGN_ - logf((float)gs + 0.5f * (c + 1.0f));
    float dw = wex - b2f(wbx[(u64)h * LCAP_ + e]);
    u32 pos = 0xFFFFFFFFu - (u32)ent;
    u32 q = pos >> 10, kk = pos & 1023u;
    u32 idx = atomicAdd(&rcnt[q], 1u);
    if (idx < RCAP_){
      rowk [((u64)(h * S_ + q)) * RCAP_ + idx] = kk;
      rowdw[((u64)(h * S_ + q)) * RCAP_ + idx] = dw;
    }
  }
  __syncthreads();

  // exact pass: rank = fh[bin] + same-bin peers greater (full u64 tie-break)
  u32 tc = topcnt; if (tc > TCAP_) tc = TCAP_;
  if ((u32)t < tc){
    u64 me = tkey[t];
    u32 fb = (((u32)(me >> 32)) - base) >> sh;
    u32 rr = fh[fb];
    for (u32 j = 0; j < tc; ++j){
      u64 cj = tkey[j];
      u32 bj = (((u32)(cj >> 32)) - base) >> sh;
      rr += (bj == fb && cj > me) ? 1u : 0u;
    }
    float wex = LOGN_ - logf((float)(rr + 1u));
    float dw = wex - b2f(wbx[(u64)h * LCAP_ + tidx[t]]);
    u32 pos = 0xFFFFFFFFu - (u32)me;
    u32 q = pos >> 10, kk = pos & 1023u;
    u32 idx = atomicAdd(&rcnt[q], 1u);
    if (idx < RCAP_){
      rowk [((u64)(h * S_ + q)) * RCAP_ + idx] = kk;
      rowdw[((u64)(h * S_ + q)) * RCAP_ + idx] = dw;
    }
  }
  __syncthreads();
  for (int i = t; i < S_; i += 1024) rowcnt[h * S_ + i] = rcnt[i];
}

// ---------------- K7: apply corrections + normalize rows ----------------
__global__ __launch_bounds__(256) void k7_fix(
    const float* __restrict__ V, const u32* __restrict__ rowcnt,
    const u32* __restrict__ rowk, const float* __restrict__ rowdw,
    const float* __restrict__ Zrow, float* __restrict__ out)
{
  int gw = (int)((blockIdx.x * blockDim.x + threadIdx.x) >> 6);
  int lane = threadIdx.x & 63;
  if (gw >= NH_ * S_) return;
  int h = gw >> 10;
  float v = out[(u64)gw * D_ + lane];
  float z = Zrow[gw];
  u32 c = rowcnt[gw]; if (c > RCAP_) c = RCAP_;
  const float* Vh = V + (u64)h * S_ * D_;
  for (u32 j = 0; j < c; ++j){
    u32 k  = rowk [(u64)gw * RCAP_ + j];
    float dw = rowdw[(u64)gw * RCAP_ + j];
    v = fmaf(dw, Vh[(u64)k * D_ + lane], v);
    z += dw;
  }
  out[(u64)gw * D_ + lane] = v / z;
}

extern "C" void kernel_launch(void* const* d_in, const int* in_sizes, int n_in,
                              void* d_out, int out_size, void* d_ws, size_t ws_size,
                              hipStream_t stream)
{
  (void)in_sizes; (void)n_in; (void)out_size;
  const float* Q = (const float*)d_in[0];
  const float* K = (const float*)d_in[1];
  const float* V = (const float*)d_in[2];
  float* out = (float*)d_out;

  uint8_t* w = (uint8_t*)d_ws;
  size_t off = 0;
  auto alloc = [&](size_t bytes) -> void* {
    void* p = w + off;
    off += (bytes + 255) & ~(size_t)255;
    return p;
  };
  float* qinv   = (float*)alloc((size_t)NH_ * S_ * 4);
  float* kinv   = (float*)alloc((size_t)NH_ * S_ * 4);
  u16*   Qn     = (u16*)  alloc((size_t)NH_ * S_ * D_ * 2);
  u16*   Kn     = (u16*)  alloc((size_t)NH_ * S_ * D_ * 2);
  u16*   VT     = (u16*)  alloc((size_t)NH_ * S_ * D_ * 2);
  u32*   Hist   = (u32*)  alloc((size_t)NH_ * BINS_ * 4);
  u16*   Wb     = (u16*)  alloc((size_t)NH_ * BINS_ * 2);
  u32*   bstar  = (u32*)  alloc((size_t)NH_ * 4);
  u32*   listCnt= (u32*)  alloc((size_t)NH_ * CNTSTRIDE_ * 4);
  u32*   kminb  = (u32*)  alloc((size_t)NH_ * CNTSTRIDE_ * 4);
  u32*   kmaxb  = (u32*)  alloc((size_t)NH_ * CNTSTRIDE_ * 4);
  u64*   list   = (u64*)  alloc((size_t)NH_ * LCAP_ * 8);
  u64*   keyex  = (u64*)  alloc((size_t)NH_ * LCAP_ * 8);
  u16*   wbx    = (u16*)  alloc((size_t)NH_ * LCAP_ * 2);
  float* Zrow   = (float*)alloc((size_t)NH_ * S_ * 4);
  u32*   rowcnt = (u32*)  alloc((size_t)NH_ * S_ * 4);
  u32*   rowk   = (u32*)  alloc((size_t)NH_ * S_ * RCAP_ * 4);
  float* rowdw  = (float*)alloc((size_t)NH_ * S_ * RCAP_ * 4);
  if (off > ws_size) return;

  hipMemsetAsync(Hist,    0,    (size_t)NH_ * BINS_ * 4,      stream);
  hipMemsetAsync(bstar,   0xFF, (size_t)NH_ * 4,              stream);
  hipMemsetAsync(listCnt, 0,    (size_t)NH_ * CNTSTRIDE_ * 4, stream);
  hipMemsetAsync(kminb,   0xFF, (size_t)NH_ * CNTSTRIDE_ * 4, stream);
  hipMemsetAsync(kmaxb,   0,    (size_t)NH_ * CNTSTRIDE_ * 4, stream);

  k1_norm <<<dim3(32768), dim3(256), 0, stream>>>(Q, K, qinv, kinv, Qn, Kn);
  k1b_vt  <<<dim3(1024),  dim3(256), 0, stream>>>(V, VT);
  k2_hist <<<dim3(256),   dim3(512), 0, stream>>>(Qn, Kn, Hist);
  k3_scan <<<dim3(64),    dim3(256), 0, stream>>>(Hist, Wb, bstar);
  k4_main <<<dim3(512),   dim3(512), 0, stream>>>(Qn, Kn, VT, Wb, bstar,
                                                  listCnt, list, Zrow, out);
  k5a_score<<<dim3(256),  dim3(256), 0, stream>>>(Q, K, qinv, kinv, list, listCnt,
                                                  keyex, wbx, kminb, kmaxb);
  k5b_rank<<<dim3(64),    dim3(1024), 0, stream>>>(keyex, wbx, listCnt, kminb, kmaxb,
                                                   rowcnt, rowk, rowdw);
  k7_fix  <<<dim3(16384), dim3(256), 0, stream>>>(V, rowcnt, rowk, rowdw, Zrow, out);
}